// Round 1
// baseline (586.074 us; speedup 1.0000x reference)
//
#include <hip/hip_runtime.h>
#include <stdint.h>

#define B_SZ 32
#define S_SZ 4096
#define H_SZ 512
#define U_SZ 512

typedef __attribute__((ext_vector_type(8))) _Float16 half8;
typedef __attribute__((ext_vector_type(4))) float floatx4;

__device__ __forceinline__ void async_copy16(const void* g, void* l) {
    __builtin_amdgcn_global_load_lds(
        (const __attribute__((address_space(1))) void*)g,
        (__attribute__((address_space(3))) void*)l, 16, 0, 0);
}

// ---------------------------------------------------------------------------
// prep (slim): no values conversion any more (scores reads fp32 directly).
//   rb in [0,1024)           : W2 fp32 -> W2s f16 [kb][kq][n][8]
//   rb in [1024,1536)        : scores[i] = bva   (atomicAdd target)
//   rb in [1536,1600)        : ctx = 0           (atomicAdd target)
//   rb in [1600,1664)        : qproj: qpb2[b][u] = q·W1 + b1 + b2
// ---------------------------------------------------------------------------
__global__ __launch_bounds__(256) void prep_kernel(
    const float* __restrict__ W2, const float* __restrict__ b1,
    const float* __restrict__ b2, const float* __restrict__ bva,
    const float* __restrict__ query, const float* __restrict__ W1,
    _Float16* __restrict__ W2s, float* __restrict__ qpb2,
    float* __restrict__ scores, float* __restrict__ ctx)
{
    const int t = threadIdx.x;
    const int rb = blockIdx.x;
    if (rb < 1024) {
        const int i = rb * 256 + t;
        const int k = i >> 9, n = i & 511;
        W2s[(k >> 5) * 16384 + ((k >> 3) & 3) * 4096 + n * 8 + (k & 7)] =
            (_Float16)W2[i];
    } else if (rb < 1536) {
        scores[(rb - 1024) * 256 + t] = *bva;
    } else if (rb < 1600) {
        ctx[(rb - 1536) * 256 + t] = 0.0f;
    } else {
        const int bq = rb - 1600;
        const int b = bq >> 1, uc = bq & 1;
        const int u = uc * 256 + t;
        const float* q  = query + b * H_SZ;
        const float* Wp = W1 + u;
        float a0 = 0.f, a1 = 0.f, a2 = 0.f, a3 = 0.f;
        for (int k = 0; k < 512; k += 4) {
            a0 = fmaf(q[k],     Wp[(size_t)k * U_SZ],       a0);
            a1 = fmaf(q[k + 1], Wp[(size_t)(k + 1) * U_SZ], a1);
            a2 = fmaf(q[k + 2], Wp[(size_t)(k + 2) * U_SZ], a2);
            a3 = fmaf(q[k + 3], Wp[(size_t)(k + 3) * U_SZ], a3);
        }
        qpb2[b * U_SZ + u] = (a0 + a1) + (a2 + a3) + b1[u] + b2[u];
    }
}

// ---------------------------------------------------------------------------
// scores v6: 128x128 tile, BK=32, 16 steps, 1 barrier/step.
// Reads RAW fp32 values (no prep conversion pass); stages via
// global_load_lds(16B), double-buffered; converts to f16 frags per step.
// XCD-aware swizzle: dispatch i lands on XCD i%8; each XCD owns a
// contiguous chunk of m-tiles so the 4 n-siblings of an m-tile run on the
// SAME XCD -> A slab (128x512 fp32 = 256 KB) is fetched from HBM once and
// L2-hit 3x (was: 4 different XCDs -> 4x HBM refetch).
// Wave w: mh=w>>1, nh=w&1 -> 4x4 tiles of 16x16, 16 MFMA/step.
// ---------------------------------------------------------------------------
__global__ __launch_bounds__(256, 4) void scores_kernel(
    const float* __restrict__ A, const _Float16* __restrict__ W2s,
    const float* __restrict__ qpb2, const float* __restrict__ va,
    float* __restrict__ scores)
{
    __shared__ __align__(16) float    Albs[2][4096];
    __shared__ __align__(16) _Float16 Blbs[2][4096];
    __shared__ float red[256];

    const int t  = threadIdx.x;
    const int w  = t >> 6, l = t & 63;
    const int c  = l & 15, g4 = l >> 4;
    const int mh = w >> 1, nh = w & 1;
    // bijective XCD swizzle (4096 % 8 == 0)
    const int bidx = (int)blockIdx.x;
    const int lb   = (bidx & 7) * 512 + (bidx >> 3);
    const int n0 = (lb & 3) * 128;
    const int m0 = (lb >> 2) * 128;
    const int b  = m0 >> 12;

    floatx4 acc[4][4];
#pragma unroll
    for (int mt = 0; mt < 4; ++mt)
#pragma unroll
        for (int nt = 0; nt < 4; ++nt) acc[mt][nt] = (floatx4)(0.0f);

    const float*    Ab0 = A + (size_t)m0 * H_SZ;
    const _Float16* Wb0 = W2s + n0 * 8;

    auto stage = [&](int kb, int buf) {
        const float* Vb = Ab0 + kb * 32;
#pragma unroll
        for (int i = 0; i < 4; ++i) {
            const int j = t + i * 256;          // 0..1023
            const int g = j >> 7, ml = j & 127;
            async_copy16(Vb + (size_t)ml * H_SZ + g * 4, &Albs[buf][j * 4]);
        }
        const _Float16* Wb = Wb0 + kb * 16384;
#pragma unroll
        for (int i = 0; i < 2; ++i) {
            const int j = t + i * 256;          // 0..511
            const int kq = j >> 7, nl = j & 127;
            async_copy16(Wb + kq * 4096 + nl * 8, &Blbs[buf][j * 8]);
        }
    };

    stage(0, 0);
    __syncthreads();

    for (int kb = 0; kb < 16; ++kb) {
        const int cur = kb & 1;
        if (kb < 15) stage(kb + 1, cur ^ 1);   // DMA lands during MFMA section
        half8 af[4];
#pragma unroll
        for (int mt = 0; mt < 4; ++mt) {
            const int ml = mh * 64 + mt * 16 + c;
            float4 lo = *(const float4*)&Albs[cur][((2 * g4)     * 128 + ml) * 4];
            float4 hi = *(const float4*)&Albs[cur][((2 * g4 + 1) * 128 + ml) * 4];
            half8 a;
            a[0] = (_Float16)lo.x; a[1] = (_Float16)lo.y;
            a[2] = (_Float16)lo.z; a[3] = (_Float16)lo.w;
            a[4] = (_Float16)hi.x; a[5] = (_Float16)hi.y;
            a[6] = (_Float16)hi.z; a[7] = (_Float16)hi.w;
            af[mt] = a;
        }
        half8 bf[4];
#pragma unroll
        for (int nt = 0; nt < 4; ++nt) {
            const int nl = nh * 64 + nt * 16 + c;
            bf[nt] = *(const half8*)&Blbs[cur][(g4 * 128 + nl) * 8];
        }
#pragma unroll
        for (int mt = 0; mt < 4; ++mt)
#pragma unroll
            for (int nt = 0; nt < 4; ++nt)
                acc[mt][nt] = __builtin_amdgcn_mfma_f32_16x16x32_f16(
                    af[mt], bf[nt], acc[mt][nt], 0, 0, 0);
        __syncthreads();
    }

    // ---- epilogue: partial over this block's 128 n-cols ----
    float qv2[4], vv[4], vv2[4];
#pragma unroll
    for (int nt = 0; nt < 4; ++nt) {
        const int n = n0 + nh * 64 + nt * 16 + c;
        const float q = qpb2[b * U_SZ + n];
        const float v = va[n];
        qv2[nt] = 2.0f * q;
        vv[nt] = v;
        vv2[nt] = 2.0f * v;
    }
#pragma unroll
    for (int mt = 0; mt < 4; ++mt) {
#pragma unroll
        for (int r = 0; r < 4; ++r) {
            float p = 0.0f;
#pragma unroll
            for (int nt = 0; nt < 4; ++nt) {
                const float ex = __expf(fmaf(acc[mt][nt][r], 2.0f, qv2[nt]));
                const float rc = __builtin_amdgcn_rcpf(ex + 1.0f);
                p = fmaf(-vv2[nt], rc, p + vv[nt]);   // += tanh(x)*va
            }
            p += __shfl_xor(p, 1);
            p += __shfl_xor(p, 2);
            p += __shfl_xor(p, 4);
            p += __shfl_xor(p, 8);
            if (c == 0)
                red[(mh * 64 + mt * 16 + g4 * 4 + r) * 2 + nh] = p;
        }
    }
    __syncthreads();
    if (t < 128)
        atomicAdd(&scores[m0 + t], red[t * 2] + red[t * 2 + 1]);
}

// ---------------------------------------------------------------------------
// sredux: per-batch softmax stats (max M, denom L)
// ---------------------------------------------------------------------------
__global__ __launch_bounds__(1024) void sredux_kernel(
    const float* __restrict__ scores, float* __restrict__ ML)
{
    __shared__ float red[16];
    __shared__ float s_max;
    const int b = blockIdx.x;
    const int t = threadIdx.x;
    float4 v = *(const float4*)(scores + b * S_SZ + t * 4);
    float m = fmaxf(fmaxf(v.x, v.y), fmaxf(v.z, v.w));
#pragma unroll
    for (int o = 32; o > 0; o >>= 1) m = fmaxf(m, __shfl_xor(m, o));
    if ((t & 63) == 0) red[t >> 6] = m;
    __syncthreads();
    if (t == 0) {
        float mm = red[0];
        for (int i = 1; i < 16; ++i) mm = fmaxf(mm, red[i]);
        s_max = mm;
    }
    __syncthreads();
    const float mm = s_max;
    float s = __expf(v.x - mm) + __expf(v.y - mm) +
              __expf(v.z - mm) + __expf(v.w - mm);
#pragma unroll
    for (int o = 32; o > 0; o >>= 1) s += __shfl_xor(s, o);
    if ((t & 63) == 0) red[t >> 6] = s;
    __syncthreads();
    if (t == 0) {
        float ss = 0.0f;
        for (int i = 0; i < 16; ++i) ss += red[i];
        ML[b * 2] = mm;
        ML[b * 2 + 1] = ss;
    }
}

// ---------------------------------------------------------------------------
// context (fp32): grid (32 sc, 32 b); block 256 = 4 waves x 32 rows each.
// ---------------------------------------------------------------------------
__global__ __launch_bounds__(256) void context_f32_kernel(
    const float* __restrict__ values, const float* __restrict__ scores,
    const float* __restrict__ ML, float* __restrict__ out)
{
    __shared__ float wl[128];
    __shared__ __align__(16) float part[4][512];
    const int sc = blockIdx.x, b = blockIdx.y;
    const int t = threadIdx.x;
    const int s0 = sc * 128;
    const float M = ML[b * 2];
    const float rL = 1.0f / ML[b * 2 + 1];
    if (t < 32) {
        float4 sv = *(const float4*)(scores + b * S_SZ + s0 + t * 4);
        float4 wv;
        wv.x = __expf(sv.x - M) * rL; wv.y = __expf(sv.y - M) * rL;
        wv.z = __expf(sv.z - M) * rL; wv.w = __expf(sv.w - M) * rL;
        *(float4*)&wl[t * 4] = wv;
        *(float4*)(out + b * S_SZ + s0 + t * 4) = wv;   // weights output
    }
    __syncthreads();

    const int g = t >> 6, l = t & 63;
    const float* vp = values + ((size_t)b * S_SZ + s0 + g * 32) * H_SZ + l * 4;
    float4 a00 = {0,0,0,0}, a01 = {0,0,0,0}, a10 = {0,0,0,0}, a11 = {0,0,0,0};
    for (int i = 0; i < 32; i += 2) {
        const float w0 = wl[g * 32 + i];
        const float w1 = wl[g * 32 + i + 1];
        const float* r0 = vp + (size_t)i * H_SZ;
        const float* r1 = r0 + H_SZ;
        float4 v00 = *(const float4*)(r0);
        float4 v01 = *(const float4*)(r0 + 256);
        float4 v10 = *(const float4*)(r1);
        float4 v11 = *(const float4*)(r1 + 256);
        a00.x = fmaf(w0, v00.x, a00.x); a00.y = fmaf(w0, v00.y, a00.y);
        a00.z = fmaf(w0, v00.z, a00.z); a00.w = fmaf(w0, v00.w, a00.w);
        a01.x = fmaf(w0, v01.x, a01.x); a01.y = fmaf(w0, v01.y, a01.y);
        a01.z = fmaf(w0, v01.z, a01.z); a01.w = fmaf(w0, v01.w, a01.w);
        a10.x = fmaf(w1, v10.x, a10.x); a10.y = fmaf(w1, v10.y, a10.y);
        a10.z = fmaf(w1, v10.z, a10.z); a10.w = fmaf(w1, v10.w, a10.w);
        a11.x = fmaf(w1, v11.x, a11.x); a11.y = fmaf(w1, v11.y, a11.y);
        a11.z = fmaf(w1, v11.z, a11.z); a11.w = fmaf(w1, v11.w, a11.w);
    }
    a00.x += a10.x; a00.y += a10.y; a00.z += a10.z; a00.w += a10.w;
    a01.x += a11.x; a01.y += a11.y; a01.z += a11.z; a01.w += a11.w;
    *(float4*)&part[g][l * 4] = a00;
    *(float4*)&part[g][256 + l * 4] = a01;
    __syncthreads();

    float* ctx = out + B_SZ * S_SZ;
#pragma unroll
    for (int rep = 0; rep < 2; ++rep) {
        const int h = rep * 256 + t;
        const float s = (part[0][h] + part[1][h]) + (part[2][h] + part[3][h]);
        atomicAdd(&ctx[b * H_SZ + h], s);
    }
}

// ---------------------------------------------------------------------------
extern "C" void kernel_launch(void* const* d_in, const int* in_sizes, int n_in,
                              void* d_out, int out_size, void* d_ws, size_t ws_size,
                              hipStream_t stream) {
    const float* query  = (const float*)d_in[0];
    const float* values = (const float*)d_in[1];
    const float* W1     = (const float*)d_in[2];
    const float* b1     = (const float*)d_in[3];
    const float* W2     = (const float*)d_in[4];
    const float* b2     = (const float*)d_in[5];
    const float* va     = (const float*)d_in[6];
    const float* bva    = (const float*)d_in[7];
    float* out = (float*)d_out;   // [32*4096 weights][32*512 context]

    char* ws = (char*)d_ws;
    float*    qpb2   = (float*)ws;                        // 64 KB
    _Float16* W2s    = (_Float16*)(ws + 65536);           // 512 KB
    float*    scores = (float*)(ws + 589824);             // 512 KB
    float*    ML     = (float*)(ws + 1114112);            // 4 KB slot

    float* ctx = out + B_SZ * S_SZ;

    prep_kernel<<<1664, 256, 0, stream>>>(
        W2, b1, b2, bva, query, W1, W2s, qpb2, scores, ctx);
    scores_kernel<<<4096, 256, 0, stream>>>(values, W2s, qpb2, va, scores);
    sredux_kernel<<<32, 1024, 0, stream>>>(scores, ML);
    context_f32_kernel<<<dim3(32, 32), 256, 0, stream>>>(values, scores, ML, out);
}

// Round 2
// 543.966 us; speedup vs baseline: 1.0774x; 1.0774x over previous
//
#include <hip/hip_runtime.h>
#include <hip/hip_bf16.h>
#include <stdint.h>

#define B_SZ 32
#define S_SZ 4096
#define H_SZ 512
#define U_SZ 512

typedef __attribute__((ext_vector_type(8))) _Float16 half8;
typedef __attribute__((ext_vector_type(4))) float floatx4;

__device__ __forceinline__ void async_copy16(const void* g, void* l) {
    __builtin_amdgcn_global_load_lds(
        (const __attribute__((address_space(1))) void*)g,
        (__attribute__((address_space(3))) void*)l, 16, 0, 0);
}

// ---------------------------------------------------------------------------
// prep (fused):
//   blocks [0, nconv)          : values fp32 -> vf16 (row-major), 8 elem/thr
//                                nconv = 67108864/(256*8) = 32768
//   rb = bid-nconv:
//     rb in [0,1024)           : W2 fp32 -> W2s f16 [kb][kq][n][8]
//     rb in [1024,1536)        : scores[i] = bva   (atomicAdd target)
//     rb in [1536,1600)        : ctx = 0           (atomicAdd target)
//     rb in [1600,1664)        : qproj: qpb2[b][u] = q·W1 + b1 + b2
// ---------------------------------------------------------------------------
__global__ __launch_bounds__(256) void prep_kernel(
    const float* __restrict__ values, const float* __restrict__ W2,
    const float* __restrict__ b1, const float* __restrict__ b2,
    const float* __restrict__ bva, const float* __restrict__ query,
    const float* __restrict__ W1, _Float16* __restrict__ W2s,
    float* __restrict__ qpb2, float* __restrict__ scores,
    float* __restrict__ ctx, _Float16* __restrict__ vf16, int nconv)
{
    const int t = threadIdx.x;
    const int bid = blockIdx.x;
    if (bid < nconv) {
        const size_t i = ((size_t)bid * 256 + t) * 8;
        float4 v0 = *(const float4*)(values + i);
        float4 v1 = *(const float4*)(values + i + 4);
        half8 h;
        h[0] = (_Float16)v0.x; h[1] = (_Float16)v0.y;
        h[2] = (_Float16)v0.z; h[3] = (_Float16)v0.w;
        h[4] = (_Float16)v1.x; h[5] = (_Float16)v1.y;
        h[6] = (_Float16)v1.z; h[7] = (_Float16)v1.w;
        *(half8*)(vf16 + i) = h;
        return;
    }
    const int rb = bid - nconv;
    if (rb < 1024) {
        const int i = rb * 256 + t;
        const int k = i >> 9, n = i & 511;
        W2s[(k >> 5) * 16384 + ((k >> 3) & 3) * 4096 + n * 8 + (k & 7)] =
            (_Float16)W2[i];
    } else if (rb < 1536) {
        scores[(rb - 1024) * 256 + t] = *bva;
    } else if (rb < 1600) {
        ctx[(rb - 1536) * 256 + t] = 0.0f;
    } else {
        const int bq = rb - 1600;
        const int b = bq >> 1, uc = bq & 1;
        const int u = uc * 256 + t;
        const float* q  = query + b * H_SZ;
        const float* Wp = W1 + u;
        float a0 = 0.f, a1 = 0.f, a2 = 0.f, a3 = 0.f;
        for (int k = 0; k < 512; k += 4) {
            a0 = fmaf(q[k],     Wp[(size_t)k * U_SZ],       a0);
            a1 = fmaf(q[k + 1], Wp[(size_t)(k + 1) * U_SZ], a1);
            a2 = fmaf(q[k + 2], Wp[(size_t)(k + 2) * U_SZ], a2);
            a3 = fmaf(q[k + 3], Wp[(size_t)(k + 3) * U_SZ], a3);
        }
        qpb2[b * U_SZ + u] = (a0 + a1) + (a2 + a3) + b1[u] + b2[u];
    }
}

// ---------------------------------------------------------------------------
// scores v7 = round-0 f16 structure + XCD swizzle.
// 128x128 tile, BK=32, 16 steps, 1 barrier/step; both operands staged via
// global_load_lds(16B), double-buffered; A pre-converted f16 (8 KB slabs,
// direct half8 frags) or fp32 fallback.
// XCD swizzle (verified in R1 counters: FETCH 540->137 MB): dispatch i lands
// on XCD i%8; lb=(i&7)*512+(i>>3) gives each XCD a contiguous lb chunk so the
// 4 n-siblings of an m-tile run temporally adjacent on the SAME XCD -> the
// 128x512 f16 A slab is HBM-fetched once, L2-hit 3x.
// Wave w: mh=w>>1, nh=w&1 -> 4x4 tiles of 16x16, 16 MFMA/step.
// ---------------------------------------------------------------------------
template <typename AT>
__global__ __launch_bounds__(256, 4) void scores_kernel(
    const AT* __restrict__ A, const _Float16* __restrict__ W2s,
    const float* __restrict__ qpb2, const float* __restrict__ va,
    float* __restrict__ scores)
{
    __shared__ __align__(16) AT       Albs[2][4096];
    __shared__ __align__(16) _Float16 Blbs[2][4096];
    __shared__ float red[256];

    const int t  = threadIdx.x;
    const int w  = t >> 6, l = t & 63;
    const int c  = l & 15, g4 = l >> 4;
    const int mh = w >> 1, nh = w & 1;
    // bijective XCD swizzle (4096 % 8 == 0)
    const int bidx = (int)blockIdx.x;
    const int lb   = (bidx & 7) * 512 + (bidx >> 3);
    const int n0 = (lb & 3) * 128;
    const int m0 = (lb >> 2) * 128;
    const int b  = m0 >> 12;

    floatx4 acc[4][4];
#pragma unroll
    for (int mt = 0; mt < 4; ++mt)
#pragma unroll
        for (int nt = 0; nt < 4; ++nt) acc[mt][nt] = (floatx4)(0.0f);

    const AT*       Ab0 = A + (size_t)m0 * H_SZ;
    const _Float16* Wb0 = W2s + n0 * 8;

    auto stage = [&](int kb, int buf) {
        const AT* Vb = Ab0 + kb * 32;
        if constexpr (sizeof(AT) == 4) {
#pragma unroll
            for (int i = 0; i < 4; ++i) {
                const int j = t + i * 256;          // 0..1023
                const int g = j >> 7, ml = j & 127;
                async_copy16(Vb + (size_t)ml * H_SZ + g * 4, &Albs[buf][j * 4]);
            }
        } else {
#pragma unroll
            for (int i = 0; i < 2; ++i) {
                const int j = t + i * 256;          // 0..511
                const int g = j >> 7, ml = j & 127;
                async_copy16(Vb + (size_t)ml * H_SZ + g * 8, &Albs[buf][j * 8]);
            }
        }
        const _Float16* Wb = Wb0 + kb * 16384;
#pragma unroll
        for (int i = 0; i < 2; ++i) {
            const int j = t + i * 256;              // 0..511
            const int kq = j >> 7, nl = j & 127;
            async_copy16(Wb + kq * 4096 + nl * 8, &Blbs[buf][j * 8]);
        }
    };

    stage(0, 0);
    __syncthreads();

    for (int kb = 0; kb < 16; ++kb) {
        const int cur = kb & 1;
        if (kb < 15) stage(kb + 1, cur ^ 1);   // DMA lands during MFMA section
        half8 af[4];
#pragma unroll
        for (int mt = 0; mt < 4; ++mt) {
            const int ml = mh * 64 + mt * 16 + c;
            if constexpr (sizeof(AT) == 4) {
                float4 lo = *(const float4*)&Albs[cur][((2 * g4)     * 128 + ml) * 4];
                float4 hi = *(const float4*)&Albs[cur][((2 * g4 + 1) * 128 + ml) * 4];
                half8 a;
                a[0] = (_Float16)lo.x; a[1] = (_Float16)lo.y;
                a[2] = (_Float16)lo.z; a[3] = (_Float16)lo.w;
                a[4] = (_Float16)hi.x; a[5] = (_Float16)hi.y;
                a[6] = (_Float16)hi.z; a[7] = (_Float16)hi.w;
                af[mt] = a;
            } else {
                af[mt] = *(const half8*)&Albs[cur][(g4 * 128 + ml) * 8];
            }
        }
        half8 bf[4];
#pragma unroll
        for (int nt = 0; nt < 4; ++nt) {
            const int nl = nh * 64 + nt * 16 + c;
            bf[nt] = *(const half8*)&Blbs[cur][(g4 * 128 + nl) * 8];
        }
#pragma unroll
        for (int mt = 0; mt < 4; ++mt)
#pragma unroll
            for (int nt = 0; nt < 4; ++nt)
                acc[mt][nt] = __builtin_amdgcn_mfma_f32_16x16x32_f16(
                    af[mt], bf[nt], acc[mt][nt], 0, 0, 0);
        __syncthreads();
    }

    // ---- epilogue: partial over this block's 128 n-cols ----
    float qv2[4], vv[4], vv2[4];
#pragma unroll
    for (int nt = 0; nt < 4; ++nt) {
        const int n = n0 + nh * 64 + nt * 16 + c;
        const float q = qpb2[b * U_SZ + n];
        const float v = va[n];
        qv2[nt] = 2.0f * q;
        vv[nt] = v;
        vv2[nt] = 2.0f * v;
    }
#pragma unroll
    for (int mt = 0; mt < 4; ++mt) {
#pragma unroll
        for (int r = 0; r < 4; ++r) {
            float p = 0.0f;
#pragma unroll
            for (int nt = 0; nt < 4; ++nt) {
                const float ex = __expf(fmaf(acc[mt][nt][r], 2.0f, qv2[nt]));
                const float rc = __builtin_amdgcn_rcpf(ex + 1.0f);
                p = fmaf(-vv2[nt], rc, p + vv[nt]);   // += tanh(x)*va
            }
            p += __shfl_xor(p, 1);
            p += __shfl_xor(p, 2);
            p += __shfl_xor(p, 4);
            p += __shfl_xor(p, 8);
            if (c == 0)
                red[(mh * 64 + mt * 16 + g4 * 4 + r) * 2 + nh] = p;
        }
    }
    __syncthreads();
    if (t < 128)
        atomicAdd(&scores[m0 + t], red[t * 2] + red[t * 2 + 1]);
}

// ---------------------------------------------------------------------------
// sredux: per-batch softmax stats (max M, denom L)
// ---------------------------------------------------------------------------
__global__ __launch_bounds__(1024) void sredux_kernel(
    const float* __restrict__ scores, float* __restrict__ ML)
{
    __shared__ float red[16];
    __shared__ float s_max;
    const int b = blockIdx.x;
    const int t = threadIdx.x;
    float4 v = *(const float4*)(scores + b * S_SZ + t * 4);
    float m = fmaxf(fmaxf(v.x, v.y), fmaxf(v.z, v.w));
#pragma unroll
    for (int o = 32; o > 0; o >>= 1) m = fmaxf(m, __shfl_xor(m, o));
    if ((t & 63) == 0) red[t >> 6] = m;
    __syncthreads();
    if (t == 0) {
        float mm = red[0];
        for (int i = 1; i < 16; ++i) mm = fmaxf(mm, red[i]);
        s_max = mm;
    }
    __syncthreads();
    const float mm = s_max;
    float s = __expf(v.x - mm) + __expf(v.y - mm) +
              __expf(v.z - mm) + __expf(v.w - mm);
#pragma unroll
    for (int o = 32; o > 0; o >>= 1) s += __shfl_xor(s, o);
    if ((t & 63) == 0) red[t >> 6] = s;
    __syncthreads();
    if (t == 0) {
        float ss = 0.0f;
        for (int i = 0; i < 16; ++i) ss += red[i];
        ML[b * 2] = mm;
        ML[b * 2 + 1] = ss;
    }
}

// ---------------------------------------------------------------------------
// context (f16): grid (32 sc, 32 b); block 256 = 4 waves x 32 rows each.
// One full 512-h row per wave-load (64 lanes x half8 = 1 KB contiguous).
// 4 independent FMA chains; cross-wave reduce in LDS; atomicAdd to ctx.
// ---------------------------------------------------------------------------
__global__ __launch_bounds__(256) void context_f16_kernel(
    const _Float16* __restrict__ vf16, const float* __restrict__ scores,
    const float* __restrict__ ML, float* __restrict__ out)
{
    __shared__ float wl[128];
    __shared__ float part[4][512];
    const int sc = blockIdx.x, b = blockIdx.y;
    const int t = threadIdx.x;
    const int s0 = sc * 128;
    const float M = ML[b * 2];
    const float rL = 1.0f / ML[b * 2 + 1];
    if (t < 32) {
        float4 sv = *(const float4*)(scores + b * S_SZ + s0 + t * 4);
        float4 wv;
        wv.x = __expf(sv.x - M) * rL; wv.y = __expf(sv.y - M) * rL;
        wv.z = __expf(sv.z - M) * rL; wv.w = __expf(sv.w - M) * rL;
        *(float4*)&wl[t * 4] = wv;
        *(float4*)(out + b * S_SZ + s0 + t * 4) = wv;   // weights output
    }
    __syncthreads();

    const int g = t >> 6, l = t & 63;
    const _Float16* vp = vf16 + ((size_t)b * S_SZ + s0 + g * 32) * H_SZ + l * 8;
    float a[4][8];
#pragma unroll
    for (int u = 0; u < 4; ++u)
#pragma unroll
        for (int e = 0; e < 8; ++e) a[u][e] = 0.0f;
    for (int i = 0; i < 32; i += 4) {
#pragma unroll
        for (int u = 0; u < 4; ++u) {
            const float wu = wl[g * 32 + i + u];
            half8 hv = *(const half8*)(vp + (size_t)(i + u) * H_SZ);
#pragma unroll
            for (int e = 0; e < 8; ++e)
                a[u][e] = fmaf(wu, (float)hv[e], a[u][e]);
        }
    }
#pragma unroll
    for (int e = 0; e < 8; ++e)
        part[g][l * 8 + e] = (a[0][e] + a[1][e]) + (a[2][e] + a[3][e]);
    __syncthreads();

    float* ctx = out + B_SZ * S_SZ;
#pragma unroll
    for (int rep = 0; rep < 2; ++rep) {
        const int h = rep * 256 + t;
        const float s = (part[0][h] + part[1][h]) + (part[2][h] + part[3][h]);
        atomicAdd(&ctx[b * H_SZ + h], s);
    }
}

// ---------------------------------------------------------------------------
// context (fp32 fallback)
// ---------------------------------------------------------------------------
__global__ __launch_bounds__(256) void context_f32_kernel(
    const float* __restrict__ values, const float* __restrict__ scores,
    const float* __restrict__ ML, float* __restrict__ out)
{
    __shared__ float wl[128];
    __shared__ __align__(16) float part[4][512];
    const int sc = blockIdx.x, b = blockIdx.y;
    const int t = threadIdx.x;
    const int s0 = sc * 128;
    const float M = ML[b * 2];
    const float rL = 1.0f / ML[b * 2 + 1];
    if (t < 32) {
        float4 sv = *(const float4*)(scores + b * S_SZ + s0 + t * 4);
        float4 wv;
        wv.x = __expf(sv.x - M) * rL; wv.y = __expf(sv.y - M) * rL;
        wv.z = __expf(sv.z - M) * rL; wv.w = __expf(sv.w - M) * rL;
        *(float4*)&wl[t * 4] = wv;
        *(float4*)(out + b * S_SZ + s0 + t * 4) = wv;
    }
    __syncthreads();

    const int g = t >> 6, l = t & 63;
    const float* vp = values + ((size_t)b * S_SZ + s0 + g * 32) * H_SZ + l * 4;
    float4 a00 = {0,0,0,0}, a01 = {0,0,0,0}, a10 = {0,0,0,0}, a11 = {0,0,0,0};
    for (int i = 0; i < 32; i += 2) {
        const float w0 = wl[g * 32 + i];
        const float w1 = wl[g * 32 + i + 1];
        const float* r0 = vp + (size_t)i * H_SZ;
        const float* r1 = r0 + H_SZ;
        float4 v00 = *(const float4*)(r0);
        float4 v01 = *(const float4*)(r0 + 256);
        float4 v10 = *(const float4*)(r1);
        float4 v11 = *(const float4*)(r1 + 256);
        a00.x = fmaf(w0, v00.x, a00.x); a00.y = fmaf(w0, v00.y, a00.y);
        a00.z = fmaf(w0, v00.z, a00.z); a00.w = fmaf(w0, v00.w, a00.w);
        a01.x = fmaf(w0, v01.x, a01.x); a01.y = fmaf(w0, v01.y, a01.y);
        a01.z = fmaf(w0, v01.z, a01.z); a01.w = fmaf(w0, v01.w, a01.w);
        a10.x = fmaf(w1, v10.x, a10.x); a10.y = fmaf(w1, v10.y, a10.y);
        a10.z = fmaf(w1, v10.z, a10.z); a10.w = fmaf(w1, v10.w, a10.w);
        a11.x = fmaf(w1, v11.x, a11.x); a11.y = fmaf(w1, v11.y, a11.y);
        a11.z = fmaf(w1, v11.z, a11.z); a11.w = fmaf(w1, v11.w, a11.w);
    }
    a00.x += a10.x; a00.y += a10.y; a00.z += a10.z; a00.w += a10.w;
    a01.x += a11.x; a01.y += a11.y; a01.z += a11.z; a01.w += a11.w;
    *(float4*)&part[g][l * 4] = a00;
    *(float4*)&part[g][256 + l * 4] = a01;
    __syncthreads();

    float* ctx = out + B_SZ * S_SZ;
#pragma unroll
    for (int rep = 0; rep < 2; ++rep) {
        const int h = rep * 256 + t;
        const float s = (part[0][h] + part[1][h]) + (part[2][h] + part[3][h]);
        atomicAdd(&ctx[b * H_SZ + h], s);
    }
}

// ---------------------------------------------------------------------------
extern "C" void kernel_launch(void* const* d_in, const int* in_sizes, int n_in,
                              void* d_out, int out_size, void* d_ws, size_t ws_size,
                              hipStream_t stream) {
    const float* query  = (const float*)d_in[0];
    const float* values = (const float*)d_in[1];
    const float* W1     = (const float*)d_in[2];
    const float* b1     = (const float*)d_in[3];
    const float* W2     = (const float*)d_in[4];
    const float* b2     = (const float*)d_in[5];
    const float* va     = (const float*)d_in[6];
    const float* bva    = (const float*)d_in[7];
    float* out = (float*)d_out;   // [32*4096 weights][32*512 context]

    char* ws = (char*)d_ws;
    float*    qpb2   = (float*)ws;                        // 64 KB
    _Float16* W2s    = (_Float16*)(ws + 65536);           // 512 KB
    float*    scores = (float*)(ws + 589824);             // 512 KB
    float*    ML     = (float*)(ws + 1114112);            // 4 KB slot
    _Float16* vf16   = (_Float16*)(ws + 1118208);         // 128 MB (f16 path)

    const size_t NEED = 1118208ull + 134217728ull;
    const bool f16path = ws_size >= NEED;
    // values has 32*4096*512 = 67,108,864 elements; 2048 per block -> 32768
    const int nconv = f16path ? 32768 : 0;

    float* ctx = out + B_SZ * S_SZ;

    prep_kernel<<<nconv + 1664, 256, 0, stream>>>(
        values, W2, b1, b2, bva, query, W1, W2s, qpb2, scores, ctx, vf16, nconv);
    if (f16path) {
        scores_kernel<_Float16><<<4096, 256, 0, stream>>>(vf16, W2s, qpb2, va, scores);
    } else {
        scores_kernel<float><<<4096, 256, 0, stream>>>(values, W2s, qpb2, va, scores);
    }
    sredux_kernel<<<32, 1024, 0, stream>>>(scores, ML);
    if (f16path) {
        context_f16_kernel<<<dim3(32, 32), 256, 0, stream>>>(vf16, scores, ML, out);
    } else {
        context_f32_kernel<<<dim3(32, 32), 256, 0, stream>>>(values, scores, ML, out);
    }
}

// Round 4
// 543.188 us; speedup vs baseline: 1.0790x; 1.0014x over previous
//
#include <hip/hip_runtime.h>
#include <stdint.h>

#define B_SZ 32
#define S_SZ 4096
#define H_SZ 512
#define U_SZ 512

typedef __attribute__((ext_vector_type(8))) _Float16 half8;
typedef __attribute__((ext_vector_type(4))) float floatx4;

__device__ __forceinline__ void async_copy16(const void* g, void* l) {
    __builtin_amdgcn_global_load_lds(
        (const __attribute__((address_space(1))) void*)g,
        (__attribute__((address_space(3))) void*)l, 16, 0, 0);
}

// ---------------------------------------------------------------------------
// prep (slim): values conversion fused into scores_kernel; no vf16 pass.
//   rb in [0,1024)           : W2 fp32 -> W2s f16 [kb][kq][n][8]
//   rb in [1024,1536)        : scores[i] = bva   (atomicAdd target)
//   rb in [1536,1600)        : ctx = 0           (atomicAdd target)
//   rb in [1600,1664)        : qproj: qpb2[b][u] = q·W1 + b1 + b2
// ---------------------------------------------------------------------------
__global__ __launch_bounds__(256) void prep_kernel(
    const float* __restrict__ W2, const float* __restrict__ b1,
    const float* __restrict__ b2, const float* __restrict__ bva,
    const float* __restrict__ query, const float* __restrict__ W1,
    _Float16* __restrict__ W2s, float* __restrict__ qpb2,
    float* __restrict__ scores, float* __restrict__ ctx)
{
    const int t = threadIdx.x;
    const int rb = blockIdx.x;
    if (rb < 1024) {
        const int i = rb * 256 + t;
        const int k = i >> 9, n = i & 511;
        W2s[(k >> 5) * 16384 + ((k >> 3) & 3) * 4096 + n * 8 + (k & 7)] =
            (_Float16)W2[i];
    } else if (rb < 1536) {
        scores[(rb - 1024) * 256 + t] = *bva;
    } else if (rb < 1600) {
        ctx[(rb - 1536) * 256 + t] = 0.0f;
    } else {
        const int bq = rb - 1600;
        const int b = bq >> 1, uc = bq & 1;
        const int u = uc * 256 + t;
        const float* q  = query + b * H_SZ;
        const float* Wp = W1 + u;
        float a0 = 0.f, a1 = 0.f, a2 = 0.f, a3 = 0.f;
        for (int k = 0; k < 512; k += 4) {
            a0 = fmaf(q[k],     Wp[(size_t)k * U_SZ],       a0);
            a1 = fmaf(q[k + 1], Wp[(size_t)(k + 1) * U_SZ], a1);
            a2 = fmaf(q[k + 2], Wp[(size_t)(k + 2) * U_SZ], a2);
            a3 = fmaf(q[k + 3], Wp[(size_t)(k + 3) * U_SZ], a3);
        }
        qpb2[b * U_SZ + u] = (a0 + a1) + (a2 + a3) + b1[u] + b2[u];
    }
}

// ---------------------------------------------------------------------------
// scores v9: fused fp32->f16 conversion, A reg-staged.
// 128x128 tile, BK=32, 16 steps, 1 barrier/step.
// Thread t owns row ml=t&127, k-chunks ga and ga+2 (ga=t>>7; chunk=8 floats):
//   global fp32 float4 x4 -> v_cvt -> 2x ds_write_b128 into Albs[chunk][ml][8]
//   (chunk c at float offset c*8, so second pair is p+16/p+20 — R3's crash
//    was p+64/p+68, reading past the end of values on the last rows).
// Issue-early / convert-late: loadA(kb+1) before the MFMA block, cvt+ds_write
// after it, so the fp32 loads land under the 16 MFMAs.
// B: W2s f16 via global_load_lds(16B), double-buffered (proven path).
// LDS f16-sized: 16+16+1 KB -> 4 blocks/CU.  XCD swizzle kept (R1-verified).
// ---------------------------------------------------------------------------
__global__ __launch_bounds__(256, 4) void scores_kernel(
    const float* __restrict__ A, const _Float16* __restrict__ W2s,
    const float* __restrict__ qpb2, const float* __restrict__ va,
    float* __restrict__ scores)
{
    __shared__ __align__(16) _Float16 Albs[2][4096];
    __shared__ __align__(16) _Float16 Blbs[2][4096];
    __shared__ float red[256];

    const int t  = threadIdx.x;
    const int w  = t >> 6, l = t & 63;
    const int c  = l & 15, g4 = l >> 4;
    const int mh = w >> 1, nh = w & 1;
    // bijective XCD swizzle (4096 % 8 == 0)
    const int bidx = (int)blockIdx.x;
    const int lb   = (bidx & 7) * 512 + (bidx >> 3);
    const int n0 = (lb & 3) * 128;
    const int m0 = (lb >> 2) * 128;
    const int b  = m0 >> 12;

    floatx4 acc[4][4];
#pragma unroll
    for (int mt = 0; mt < 4; ++mt)
#pragma unroll
        for (int nt = 0; nt < 4; ++nt) acc[mt][nt] = (floatx4)(0.0f);

    const int ml = t & 127;
    const int ga = t >> 7;                          // 0 or 1
    const float*    Arow = A + (size_t)(m0 + ml) * H_SZ;
    const _Float16* Wb0  = W2s + n0 * 8;

    float4 ra0, ra1, ra2, ra3;
    auto loadA = [&](int kb) {
        const float* p = Arow + kb * 32 + ga * 8;
        ra0 = *(const float4*)(p);          // chunk ga,   e 0..3
        ra1 = *(const float4*)(p + 4);      // chunk ga,   e 4..7
        ra2 = *(const float4*)(p + 16);     // chunk ga+2, e 0..3
        ra3 = *(const float4*)(p + 20);     // chunk ga+2, e 4..7
    };
    auto cvtwrite = [&](int buf) {
        half8 h0, h1;
        h0[0] = (_Float16)ra0.x; h0[1] = (_Float16)ra0.y;
        h0[2] = (_Float16)ra0.z; h0[3] = (_Float16)ra0.w;
        h0[4] = (_Float16)ra1.x; h0[5] = (_Float16)ra1.y;
        h0[6] = (_Float16)ra1.z; h0[7] = (_Float16)ra1.w;
        h1[0] = (_Float16)ra2.x; h1[1] = (_Float16)ra2.y;
        h1[2] = (_Float16)ra2.z; h1[3] = (_Float16)ra2.w;
        h1[4] = (_Float16)ra3.x; h1[5] = (_Float16)ra3.y;
        h1[6] = (_Float16)ra3.z; h1[7] = (_Float16)ra3.w;
        *(half8*)&Albs[buf][(ga * 128 + ml) * 8]       = h0;
        *(half8*)&Albs[buf][((ga + 2) * 128 + ml) * 8] = h1;
    };
    auto stageB = [&](int kb, int buf) {
        const _Float16* Wb = Wb0 + kb * 16384;
#pragma unroll
        for (int i = 0; i < 2; ++i) {
            const int j = t + i * 256;              // 0..511
            const int kq = j >> 7, nl = j & 127;
            async_copy16(Wb + kq * 4096 + nl * 8, &Blbs[buf][j * 8]);
        }
    };

    // prologue: tile 0 (latency exposed once)
    stageB(0, 0);
    loadA(0);
    cvtwrite(0);
    __syncthreads();

    for (int kb = 0; kb < 16; ++kb) {
        const int cur = kb & 1;
        if (kb < 15) {
            loadA(kb + 1);                 // issue early: lands under MFMA
            stageB(kb + 1, cur ^ 1);
        }
        half8 af[4];
#pragma unroll
        for (int mt = 0; mt < 4; ++mt) {
            const int mll = mh * 64 + mt * 16 + c;
            af[mt] = *(const half8*)&Albs[cur][(g4 * 128 + mll) * 8];
        }
        half8 bf[4];
#pragma unroll
        for (int nt = 0; nt < 4; ++nt) {
            const int nl = nh * 64 + nt * 16 + c;
            bf[nt] = *(const half8*)&Blbs[cur][(g4 * 128 + nl) * 8];
        }
#pragma unroll
        for (int mt = 0; mt < 4; ++mt)
#pragma unroll
            for (int nt = 0; nt < 4; ++nt)
                acc[mt][nt] = __builtin_amdgcn_mfma_f32_16x16x32_f16(
                    af[mt], bf[nt], acc[mt][nt], 0, 0, 0);
        if (kb < 15) cvtwrite(cur ^ 1);   // convert late, write next buf
        __syncthreads();
    }

    // ---- epilogue: partial over this block's 128 n-cols ----
    float qv2[4], vv[4], vv2[4];
#pragma unroll
    for (int nt = 0; nt < 4; ++nt) {
        const int n = n0 + nh * 64 + nt * 16 + c;
        const float q = qpb2[b * U_SZ + n];
        const float v = va[n];
        qv2[nt] = 2.0f * q;
        vv[nt] = v;
        vv2[nt] = 2.0f * v;
    }
#pragma unroll
    for (int mt = 0; mt < 4; ++mt) {
#pragma unroll
        for (int r = 0; r < 4; ++r) {
            float p = 0.0f;
#pragma unroll
            for (int nt = 0; nt < 4; ++nt) {
                const float ex = __expf(fmaf(acc[mt][nt][r], 2.0f, qv2[nt]));
                const float rc = __builtin_amdgcn_rcpf(ex + 1.0f);
                p = fmaf(-vv2[nt], rc, p + vv[nt]);   // += tanh(x)*va
            }
            p += __shfl_xor(p, 1);
            p += __shfl_xor(p, 2);
            p += __shfl_xor(p, 4);
            p += __shfl_xor(p, 8);
            if (c == 0)
                red[(mh * 64 + mt * 16 + g4 * 4 + r) * 2 + nh] = p;
        }
    }
    __syncthreads();
    if (t < 128)
        atomicAdd(&scores[m0 + t], red[t * 2] + red[t * 2 + 1]);
}

// ---------------------------------------------------------------------------
// sredux: per-batch softmax stats (max M, denom L)
// ---------------------------------------------------------------------------
__global__ __launch_bounds__(1024) void sredux_kernel(
    const float* __restrict__ scores, float* __restrict__ ML)
{
    __shared__ float red[16];
    __shared__ float s_max;
    const int b = blockIdx.x;
    const int t = threadIdx.x;
    float4 v = *(const float4*)(scores + b * S_SZ + t * 4);
    float m = fmaxf(fmaxf(v.x, v.y), fmaxf(v.z, v.w));
#pragma unroll
    for (int o = 32; o > 0; o >>= 1) m = fmaxf(m, __shfl_xor(m, o));
    if ((t & 63) == 0) red[t >> 6] = m;
    __syncthreads();
    if (t == 0) {
        float mm = red[0];
        for (int i = 1; i < 16; ++i) mm = fmaxf(mm, red[i]);
        s_max = mm;
    }
    __syncthreads();
    const float mm = s_max;
    float s = __expf(v.x - mm) + __expf(v.y - mm) +
              __expf(v.z - mm) + __expf(v.w - mm);
#pragma unroll
    for (int o = 32; o > 0; o >>= 1) s += __shfl_xor(s, o);
    if ((t & 63) == 0) red[t >> 6] = s;
    __syncthreads();
    if (t == 0) {
        float ss = 0.0f;
        for (int i = 0; i < 16; ++i) ss += red[i];
        ML[b * 2] = mm;
        ML[b * 2 + 1] = ss;
    }
}

// ---------------------------------------------------------------------------
// context (fp32): grid (32 sc, 32 b); block 256 = 4 waves x 32 rows each.
// Reads raw values (256 MB) — same total traffic as the old f16 round-trip
// (128 MB write + 128 MB read) without the scatter-write risk.
// ---------------------------------------------------------------------------
__global__ __launch_bounds__(256) void context_f32_kernel(
    const float* __restrict__ values, const float* __restrict__ scores,
    const float* __restrict__ ML, float* __restrict__ out)
{
    __shared__ float wl[128];
    __shared__ __align__(16) float part[4][512];
    const int sc = blockIdx.x, b = blockIdx.y;
    const int t = threadIdx.x;
    const int s0 = sc * 128;
    const float M = ML[b * 2];
    const float rL = 1.0f / ML[b * 2 + 1];
    if (t < 32) {
        float4 sv = *(const float4*)(scores + b * S_SZ + s0 + t * 4);
        float4 wv;
        wv.x = __expf(sv.x - M) * rL; wv.y = __expf(sv.y - M) * rL;
        wv.z = __expf(sv.z - M) * rL; wv.w = __expf(sv.w - M) * rL;
        *(float4*)&wl[t * 4] = wv;
        *(float4*)(out + b * S_SZ + s0 + t * 4) = wv;   // weights output
    }
    __syncthreads();

    const int g = t >> 6, l = t & 63;
    const float* vp = values + ((size_t)b * S_SZ + s0 + g * 32) * H_SZ + l * 4;
    float4 a00 = {0,0,0,0}, a01 = {0,0,0,0}, a10 = {0,0,0,0}, a11 = {0,0,0,0};
    for (int i = 0; i < 32; i += 2) {
        const float w0 = wl[g * 32 + i];
        const float w1 = wl[g * 32 + i + 1];
        const float* r0 = vp + (size_t)i * H_SZ;
        const float* r1 = r0 + H_SZ;
        float4 v00 = *(const float4*)(r0);
        float4 v01 = *(const float4*)(r0 + 256);
        float4 v10 = *(const float4*)(r1);
        float4 v11 = *(const float4*)(r1 + 256);
        a00.x = fmaf(w0, v00.x, a00.x); a00.y = fmaf(w0, v00.y, a00.y);
        a00.z = fmaf(w0, v00.z, a00.z); a00.w = fmaf(w0, v00.w, a00.w);
        a01.x = fmaf(w0, v01.x, a01.x); a01.y = fmaf(w0, v01.y, a01.y);
        a01.z = fmaf(w0, v01.z, a01.z); a01.w = fmaf(w0, v01.w, a01.w);
        a10.x = fmaf(w1, v10.x, a10.x); a10.y = fmaf(w1, v10.y, a10.y);
        a10.z = fmaf(w1, v10.z, a10.z); a10.w = fmaf(w1, v10.w, a10.w);
        a11.x = fmaf(w1, v11.x, a11.x); a11.y = fmaf(w1, v11.y, a11.y);
        a11.z = fmaf(w1, v11.z, a11.z); a11.w = fmaf(w1, v11.w, a11.w);
    }
    a00.x += a10.x; a00.y += a10.y; a00.z += a10.z; a00.w += a10.w;
    a01.x += a11.x; a01.y += a11.y; a01.z += a11.z; a01.w += a11.w;
    *(float4*)&part[g][l * 4] = a00;
    *(float4*)&part[g][256 + l * 4] = a01;
    __syncthreads();

    float* ctx = out + B_SZ * S_SZ;
#pragma unroll
    for (int rep = 0; rep < 2; ++rep) {
        const int h = rep * 256 + t;
        const float s = (part[0][h] + part[1][h]) + (part[2][h] + part[3][h]);
        atomicAdd(&ctx[b * H_SZ + h], s);
    }
}

// ---------------------------------------------------------------------------
extern "C" void kernel_launch(void* const* d_in, const int* in_sizes, int n_in,
                              void* d_out, int out_size, void* d_ws, size_t ws_size,
                              hipStream_t stream) {
    const float* query  = (const float*)d_in[0];
    const float* values = (const float*)d_in[1];
    const float* W1     = (const float*)d_in[2];
    const float* b1     = (const float*)d_in[3];
    const float* W2     = (const float*)d_in[4];
    const float* b2     = (const float*)d_in[5];
    const float* va     = (const float*)d_in[6];
    const float* bva    = (const float*)d_in[7];
    float* out = (float*)d_out;   // [32*4096 weights][32*512 context]

    char* ws = (char*)d_ws;
    float*    qpb2   = (float*)ws;                        // 64 KB
    _Float16* W2s    = (_Float16*)(ws + 65536);           // 512 KB
    float*    scores = (float*)(ws + 589824);             // 512 KB
    float*    ML     = (float*)(ws + 1114112);            // 4 KB slot

    float* ctx = out + B_SZ * S_SZ;

    prep_kernel<<<1664, 256, 0, stream>>>(
        W2, b1, b2, bva, query, W1, W2s, qpb2, scores, ctx);
    scores_kernel<<<4096, 256, 0, stream>>>(values, W2s, qpb2, va, scores);
    sredux_kernel<<<32, 1024, 0, stream>>>(scores, ML);
    context_f32_kernel<<<dim3(32, 32), 256, 0, stream>>>(values, scores, ML, out);
}

// Round 5
// 519.265 us; speedup vs baseline: 1.1287x; 1.0461x over previous
//
#include <hip/hip_runtime.h>
#include <stdint.h>

#define B_SZ 32
#define S_SZ 4096
#define H_SZ 512
#define U_SZ 512

typedef __attribute__((ext_vector_type(8))) _Float16 half8;
typedef __attribute__((ext_vector_type(4))) float floatx4;

__device__ __forceinline__ void async_copy16(const void* g, void* l) {
    __builtin_amdgcn_global_load_lds(
        (const __attribute__((address_space(1))) void*)g,
        (__attribute__((address_space(3))) void*)l, 16, 0, 0);
}

// ---------------------------------------------------------------------------
// prep (slim): values conversion fused into scores_kernel; no vf16 pass.
//   rb in [0,1024)           : W2 fp32 -> W2s f16 [kb][kq][n][8]
//   rb in [1024,1536)        : scores[i] = bva   (atomicAdd target)
//   rb in [1536,1600)        : ctx = 0           (atomicAdd target)
//   rb in [1600,1664)        : qproj: qpb2[b][u] = q·W1 + b1 + b2
// ---------------------------------------------------------------------------
__global__ __launch_bounds__(256) void prep_kernel(
    const float* __restrict__ W2, const float* __restrict__ b1,
    const float* __restrict__ b2, const float* __restrict__ bva,
    const float* __restrict__ query, const float* __restrict__ W1,
    _Float16* __restrict__ W2s, float* __restrict__ qpb2,
    float* __restrict__ scores, float* __restrict__ ctx)
{
    const int t = threadIdx.x;
    const int rb = blockIdx.x;
    if (rb < 1024) {
        const int i = rb * 256 + t;
        const int k = i >> 9, n = i & 511;
        W2s[(k >> 5) * 16384 + ((k >> 3) & 3) * 4096 + n * 8 + (k & 7)] =
            (_Float16)W2[i];
    } else if (rb < 1536) {
        scores[(rb - 1024) * 256 + t] = *bva;
    } else if (rb < 1600) {
        ctx[(rb - 1536) * 256 + t] = 0.0f;
    } else {
        const int bq = rb - 1600;
        const int b = bq >> 1, uc = bq & 1;
        const int u = uc * 256 + t;
        const float* q  = query + b * H_SZ;
        const float* Wp = W1 + u;
        float a0 = 0.f, a1 = 0.f, a2 = 0.f, a3 = 0.f;
        for (int k = 0; k < 512; k += 4) {
            a0 = fmaf(q[k],     Wp[(size_t)k * U_SZ],       a0);
            a1 = fmaf(q[k + 1], Wp[(size_t)(k + 1) * U_SZ], a1);
            a2 = fmaf(q[k + 2], Wp[(size_t)(k + 2) * U_SZ], a2);
            a3 = fmaf(q[k + 3], Wp[(size_t)(k + 3) * U_SZ], a3);
        }
        qpb2[b * U_SZ + u] = (a0 + a1) + (a2 + a3) + b1[u] + b2[u];
    }
}

// ---------------------------------------------------------------------------
// scores v10: fused fp32->f16, A reg-staged with COALESCED loads.
// R4's loadA mapped lane-consecutive threads to consecutive ROWS (stride
// 2 KB) -> 64 cache-line requests per wave-load, ~1024 line-req/block/step
// -> issue/latency bound (MfmaUtil 13%, VALU 17%, HBM 8%, all idle).
// Now: j = t + 256*i, row = j>>2, q = j&3 -> 4 lanes cover one row's 128 B
// (16 line-req per wave-load, 4x fewer). Converted half8 lands in LDS at
//   byte = q*2048 + (row*16 ^ (q<<5))
// XOR keeps b128 writes conflict-free (bank = 4r%32 ^ 8q: 2 lanes/quad) and
// frag reads (g4*2048 + (ml*16 ^ (g4<<5))) 2-way (free). Same logical A
// content and same barrier structure as R4 (which passed).
// B: W2s f16 via global_load_lds(16B), double-buffered (proven path).
// LDS f16-sized: 16+16+1 KB -> 4 blocks/CU.  XCD swizzle kept (R1-verified).
// ---------------------------------------------------------------------------
__global__ __launch_bounds__(256, 4) void scores_kernel(
    const float* __restrict__ A, const _Float16* __restrict__ W2s,
    const float* __restrict__ qpb2, const float* __restrict__ va,
    float* __restrict__ scores)
{
    __shared__ __align__(16) _Float16 Albs[2][4096];
    __shared__ __align__(16) _Float16 Blbs[2][4096];
    __shared__ float red[256];

    const int t  = threadIdx.x;
    const int w  = t >> 6, l = t & 63;
    const int c  = l & 15, g4 = l >> 4;
    const int mh = w >> 1, nh = w & 1;
    // bijective XCD swizzle (4096 % 8 == 0)
    const int bidx = (int)blockIdx.x;
    const int lb   = (bidx & 7) * 512 + (bidx >> 3);
    const int n0 = (lb & 3) * 128;
    const int m0 = (lb >> 2) * 128;
    const int b  = m0 >> 12;

    floatx4 acc[4][4];
#pragma unroll
    for (int mt = 0; mt < 4; ++mt)
#pragma unroll
        for (int nt = 0; nt < 4; ++nt) acc[mt][nt] = (floatx4)(0.0f);

    // A staging geometry (coalesced): piece i in {0,1}: j = t + 256*i,
    // row = j>>2 in [0,128), q = j&3 (8-float chunk of the 32-k slab).
    const int j0 = t,        j1 = t + 256;
    const int r0_ = j0 >> 2, q0_ = j0 & 3;
    const int r1_ = j1 >> 2, q1_ = j1 & 3;
    const float* Ap0 = A + (size_t)(m0 + r0_) * H_SZ + q0_ * 8;
    const float* Ap1 = A + (size_t)(m0 + r1_) * H_SZ + q1_ * 8;
    const int wo0 = q0_ * 2048 + ((r0_ * 16) ^ (q0_ << 5));   // LDS byte offs
    const int wo1 = q1_ * 2048 + ((r1_ * 16) ^ (q1_ << 5));
    const _Float16* Wb0 = W2s + n0 * 8;

    float4 ra0, ra1, ra2, ra3;
    auto loadA = [&](int kb) {
        const float* p0 = Ap0 + kb * 32;
        const float* p1 = Ap1 + kb * 32;
        ra0 = *(const float4*)(p0);         // (r0, q0) e 0..3
        ra1 = *(const float4*)(p0 + 4);     // (r0, q0) e 4..7
        ra2 = *(const float4*)(p1);         // (r1, q1) e 0..3
        ra3 = *(const float4*)(p1 + 4);     // (r1, q1) e 4..7
    };
    auto cvtwrite = [&](int buf) {
        half8 h0, h1;
        h0[0] = (_Float16)ra0.x; h0[1] = (_Float16)ra0.y;
        h0[2] = (_Float16)ra0.z; h0[3] = (_Float16)ra0.w;
        h0[4] = (_Float16)ra1.x; h0[5] = (_Float16)ra1.y;
        h0[6] = (_Float16)ra1.z; h0[7] = (_Float16)ra1.w;
        h1[0] = (_Float16)ra2.x; h1[1] = (_Float16)ra2.y;
        h1[2] = (_Float16)ra2.z; h1[3] = (_Float16)ra2.w;
        h1[4] = (_Float16)ra3.x; h1[5] = (_Float16)ra3.y;
        h1[6] = (_Float16)ra3.z; h1[7] = (_Float16)ra3.w;
        *(half8*)((char*)&Albs[buf][0] + wo0) = h0;
        *(half8*)((char*)&Albs[buf][0] + wo1) = h1;
    };
    auto stageB = [&](int kb, int buf) {
        const _Float16* Wb = Wb0 + kb * 16384;
#pragma unroll
        for (int i = 0; i < 2; ++i) {
            const int j = t + i * 256;              // 0..511
            const int kq = j >> 7, nl = j & 127;
            async_copy16(Wb + kq * 4096 + nl * 8, &Blbs[buf][j * 8]);
        }
    };

    // prologue: tile 0 (latency exposed once)
    stageB(0, 0);
    loadA(0);
    cvtwrite(0);
    __syncthreads();

    for (int kb = 0; kb < 16; ++kb) {
        const int cur = kb & 1;
        if (kb < 15) {
            loadA(kb + 1);                 // issue early: lands under MFMA
            stageB(kb + 1, cur ^ 1);
        }
        half8 af[4];
#pragma unroll
        for (int mt = 0; mt < 4; ++mt) {
            const int mll = mh * 64 + mt * 16 + c;
            af[mt] = *(const half8*)((const char*)&Albs[cur][0] +
                                     g4 * 2048 + ((mll * 16) ^ (g4 << 5)));
        }
        half8 bf[4];
#pragma unroll
        for (int nt = 0; nt < 4; ++nt) {
            const int nl = nh * 64 + nt * 16 + c;
            bf[nt] = *(const half8*)&Blbs[cur][(g4 * 128 + nl) * 8];
        }
#pragma unroll
        for (int mt = 0; mt < 4; ++mt)
#pragma unroll
            for (int nt = 0; nt < 4; ++nt)
                acc[mt][nt] = __builtin_amdgcn_mfma_f32_16x16x32_f16(
                    af[mt], bf[nt], acc[mt][nt], 0, 0, 0);
        if (kb < 15) cvtwrite(cur ^ 1);   // convert late, write next buf
        __syncthreads();
    }

    // ---- epilogue: partial over this block's 128 n-cols ----
    float qv2[4], vv[4], vv2[4];
#pragma unroll
    for (int nt = 0; nt < 4; ++nt) {
        const int n = n0 + nh * 64 + nt * 16 + c;
        const float q = qpb2[b * U_SZ + n];
        const float v = va[n];
        qv2[nt] = 2.0f * q;
        vv[nt] = v;
        vv2[nt] = 2.0f * v;
    }
#pragma unroll
    for (int mt = 0; mt < 4; ++mt) {
#pragma unroll
        for (int r = 0; r < 4; ++r) {
            float p = 0.0f;
#pragma unroll
            for (int nt = 0; nt < 4; ++nt) {
                const float ex = __expf(fmaf(acc[mt][nt][r], 2.0f, qv2[nt]));
                const float rc = __builtin_amdgcn_rcpf(ex + 1.0f);
                p = fmaf(-vv2[nt], rc, p + vv[nt]);   // += tanh(x)*va
            }
            p += __shfl_xor(p, 1);
            p += __shfl_xor(p, 2);
            p += __shfl_xor(p, 4);
            p += __shfl_xor(p, 8);
            if (c == 0)
                red[(mh * 64 + mt * 16 + g4 * 4 + r) * 2 + nh] = p;
        }
    }
    __syncthreads();
    if (t < 128)
        atomicAdd(&scores[m0 + t], red[t * 2] + red[t * 2 + 1]);
}

// ---------------------------------------------------------------------------
// sredux: per-batch softmax stats (max M, denom L)
// ---------------------------------------------------------------------------
__global__ __launch_bounds__(1024) void sredux_kernel(
    const float* __restrict__ scores, float* __restrict__ ML)
{
    __shared__ float red[16];
    __shared__ float s_max;
    const int b = blockIdx.x;
    const int t = threadIdx.x;
    float4 v = *(const float4*)(scores + b * S_SZ + t * 4);
    float m = fmaxf(fmaxf(v.x, v.y), fmaxf(v.z, v.w));
#pragma unroll
    for (int o = 32; o > 0; o >>= 1) m = fmaxf(m, __shfl_xor(m, o));
    if ((t & 63) == 0) red[t >> 6] = m;
    __syncthreads();
    if (t == 0) {
        float mm = red[0];
        for (int i = 1; i < 16; ++i) mm = fmaxf(mm, red[i]);
        s_max = mm;
    }
    __syncthreads();
    const float mm = s_max;
    float s = __expf(v.x - mm) + __expf(v.y - mm) +
              __expf(v.z - mm) + __expf(v.w - mm);
#pragma unroll
    for (int o = 32; o > 0; o >>= 1) s += __shfl_xor(s, o);
    if ((t & 63) == 0) red[t >> 6] = s;
    __syncthreads();
    if (t == 0) {
        float ss = 0.0f;
        for (int i = 0; i < 16; ++i) ss += red[i];
        ML[b * 2] = mm;
        ML[b * 2 + 1] = ss;
    }
}

// ---------------------------------------------------------------------------
// context (fp32): grid (32 sc, 32 b); block 256 = 4 waves x 32 rows each.
// ---------------------------------------------------------------------------
__global__ __launch_bounds__(256) void context_f32_kernel(
    const float* __restrict__ values, const float* __restrict__ scores,
    const float* __restrict__ ML, float* __restrict__ out)
{
    __shared__ float wl[128];
    __shared__ __align__(16) float part[4][512];
    const int sc = blockIdx.x, b = blockIdx.y;
    const int t = threadIdx.x;
    const int s0 = sc * 128;
    const float M = ML[b * 2];
    const float rL = 1.0f / ML[b * 2 + 1];
    if (t < 32) {
        float4 sv = *(const float4*)(scores + b * S_SZ + s0 + t * 4);
        float4 wv;
        wv.x = __expf(sv.x - M) * rL; wv.y = __expf(sv.y - M) * rL;
        wv.z = __expf(sv.z - M) * rL; wv.w = __expf(sv.w - M) * rL;
        *(float4*)&wl[t * 4] = wv;
        *(float4*)(out + b * S_SZ + s0 + t * 4) = wv;   // weights output
    }
    __syncthreads();

    const int g = t >> 6, l = t & 63;
    const float* vp = values + ((size_t)b * S_SZ + s0 + g * 32) * H_SZ + l * 4;
    float4 a00 = {0,0,0,0}, a01 = {0,0,0,0}, a10 = {0,0,0,0}, a11 = {0,0,0,0};
    for (int i = 0; i < 32; i += 2) {
        const float w0 = wl[g * 32 + i];
        const float w1 = wl[g * 32 + i + 1];
        const float* r0 = vp + (size_t)i * H_SZ;
        const float* r1 = r0 + H_SZ;
        float4 v00 = *(const float4*)(r0);
        float4 v01 = *(const float4*)(r0 + 256);
        float4 v10 = *(const float4*)(r1);
        float4 v11 = *(const float4*)(r1 + 256);
        a00.x = fmaf(w0, v00.x, a00.x); a00.y = fmaf(w0, v00.y, a00.y);
        a00.z = fmaf(w0, v00.z, a00.z); a00.w = fmaf(w0, v00.w, a00.w);
        a01.x = fmaf(w0, v01.x, a01.x); a01.y = fmaf(w0, v01.y, a01.y);
        a01.z = fmaf(w0, v01.z, a01.z); a01.w = fmaf(w0, v01.w, a01.w);
        a10.x = fmaf(w1, v10.x, a10.x); a10.y = fmaf(w1, v10.y, a10.y);
        a10.z = fmaf(w1, v10.z, a10.z); a10.w = fmaf(w1, v10.w, a10.w);
        a11.x = fmaf(w1, v11.x, a11.x); a11.y = fmaf(w1, v11.y, a11.y);
        a11.z = fmaf(w1, v11.z, a11.z); a11.w = fmaf(w1, v11.w, a11.w);
    }
    a00.x += a10.x; a00.y += a10.y; a00.z += a10.z; a00.w += a10.w;
    a01.x += a11.x; a01.y += a11.y; a01.z += a11.z; a01.w += a11.w;
    *(float4*)&part[g][l * 4] = a00;
    *(float4*)&part[g][256 + l * 4] = a01;
    __syncthreads();

    float* ctx = out + B_SZ * S_SZ;
#pragma unroll
    for (int rep = 0; rep < 2; ++rep) {
        const int h = rep * 256 + t;
        const float s = (part[0][h] + part[1][h]) + (part[2][h] + part[3][h]);
        atomicAdd(&ctx[b * H_SZ + h], s);
    }
}

// ---------------------------------------------------------------------------
extern "C" void kernel_launch(void* const* d_in, const int* in_sizes, int n_in,
                              void* d_out, int out_size, void* d_ws, size_t ws_size,
                              hipStream_t stream) {
    const float* query  = (const float*)d_in[0];
    const float* values = (const float*)d_in[1];
    const float* W1     = (const float*)d_in[2];
    const float* b1     = (const float*)d_in[3];
    const float* W2     = (const float*)d_in[4];
    const float* b2     = (const float*)d_in[5];
    const float* va     = (const float*)d_in[6];
    const float* bva    = (const float*)d_in[7];
    float* out = (float*)d_out;   // [32*4096 weights][32*512 context]

    char* ws = (char*)d_ws;
    float*    qpb2   = (float*)ws;                        // 64 KB
    _Float16* W2s    = (_Float16*)(ws + 65536);           // 512 KB
    float*    scores = (float*)(ws + 589824);             // 512 KB
    float*    ML     = (float*)(ws + 1114112);            // 4 KB slot

    float* ctx = out + B_SZ * S_SZ;

    prep_kernel<<<1664, 256, 0, stream>>>(
        W2, b1, b2, bva, query, W1, W2s, qpb2, scores, ctx);
    scores_kernel<<<4096, 256, 0, stream>>>(values, W2s, qpb2, va, scores);
    sredux_kernel<<<32, 1024, 0, stream>>>(scores, ML);
    context_f32_kernel<<<dim3(32, 32), 256, 0, stream>>>(values, scores, ML, out);
}